// Round 1
// baseline (110.583 us; speedup 1.0000x reference)
//
#include <hip/hip_runtime.h>

// Proximity: mean over B of clipped L2 distance between L2-normalized x row
// and its label's L2-normalized center row.
// dist[i] = sxx/nx^2 + scc/nc^2 - 2*sxc/(nx*nc),  nx=max(sqrt(sxx),eps) etc.

#define EPS_MIN 1e-12f
#define CLAMP_MAX 1e12f

typedef float v4f __attribute__((ext_vector_type(4)));

// One wave (64 lanes) per sample; 4 waves per block; no inter-wave coupling.
// x is streamed with non-temporal loads (no reuse -> don't evict centers from
// the 4 MiB per-XCD L2); centers (4.1 MB total, ~16x reuse) use normal cached
// loads so they stay L2-resident.
__global__ __launch_bounds__(256) void prox_partial_kernel(
    const float* __restrict__ x,
    const int* __restrict__ labels,
    const float* __restrict__ centers,
    float* __restrict__ partial,
    int Bn, int Dn)
{
    const int wave = threadIdx.x >> 6;
    const int lane = threadIdx.x & 63;
    const int sample = (blockIdx.x << 2) + wave;
    if (sample >= Bn) return;

    const float* xr = x + (size_t)sample * Dn;
    const int lbl = labels[sample];
    const float* cr = centers + (size_t)lbl * Dn;

    float sxx = 0.f, scc = 0.f, sxc = 0.f;

    if (Dn == 1024) {
        // 256 float4 per row, 64 lanes -> exactly 4 float4 per lane.
        // Fully unrolled so all 8 vector loads are in flight together.
        #pragma unroll
        for (int it = 0; it < 4; ++it) {
            const int idx = (lane + (it << 6)) << 2;
            v4f xv = __builtin_nontemporal_load((const v4f*)(xr + idx));
            v4f cv = *(const v4f*)(cr + idx);
            sxx += xv[0] * xv[0] + xv[1] * xv[1] + xv[2] * xv[2] + xv[3] * xv[3];
            scc += cv[0] * cv[0] + cv[1] * cv[1] + cv[2] * cv[2] + cv[3] * cv[3];
            sxc += xv[0] * cv[0] + xv[1] * cv[1] + xv[2] * cv[2] + xv[3] * cv[3];
        }
    } else {
        #pragma unroll 4
        for (int f4 = lane; f4 * 4 < Dn; f4 += 64) {
            const int idx = f4 * 4;
            v4f xv = __builtin_nontemporal_load((const v4f*)(xr + idx));
            v4f cv = *(const v4f*)(cr + idx);
            sxx += xv[0] * xv[0] + xv[1] * xv[1] + xv[2] * xv[2] + xv[3] * xv[3];
            scc += cv[0] * cv[0] + cv[1] * cv[1] + cv[2] * cv[2] + cv[3] * cv[3];
            sxc += xv[0] * cv[0] + xv[1] * cv[1] + xv[2] * cv[2] + xv[3] * cv[3];
        }
    }

    // 64-lane butterfly reduction (3 independent chains overlap).
    #pragma unroll
    for (int off = 32; off > 0; off >>= 1) {
        sxx += __shfl_down(sxx, off, 64);
        scc += __shfl_down(scc, off, 64);
        sxc += __shfl_down(sxc, off, 64);
    }
    if (lane == 0) {
        float nx = fmaxf(sqrtf(sxx), EPS_MIN);
        float nc = fmaxf(sqrtf(scc), EPS_MIN);
        float ixx = sxx / (nx * nx);   // (||x||/nx)^2, == 1 unless degenerate
        float icc = scc / (nc * nc);
        float dot = sxc / (nx * nc);
        float d = ixx + icc - 2.0f * dot;
        partial[sample] = fminf(fmaxf(d, EPS_MIN), CLAMP_MAX);
    }
}

// Single-block deterministic reduction of the per-sample partials -> mean.
__global__ __launch_bounds__(256) void prox_final_kernel(
    const float* __restrict__ partial, float* __restrict__ out,
    int n, float inv_B)
{
    float s = 0.f;
    const int nv = n >> 2;                 // n = 16384 -> 4096 float4
    const v4f* pv = (const v4f*)partial;
    for (int i = threadIdx.x; i < nv; i += 256) {
        v4f v = pv[i];
        s += (v[0] + v[1]) + (v[2] + v[3]);
    }
    for (int i = (nv << 2) + threadIdx.x; i < n; i += 256) s += partial[i];

    __shared__ float smem[4];
    #pragma unroll
    for (int off = 32; off > 0; off >>= 1) s += __shfl_down(s, off, 64);
    const int wave = threadIdx.x >> 6;
    const int lane = threadIdx.x & 63;
    if (lane == 0) smem[wave] = s;
    __syncthreads();
    if (threadIdx.x == 0)
        out[0] = (smem[0] + smem[1] + smem[2] + smem[3]) * inv_B;
}

extern "C" void kernel_launch(void* const* d_in, const int* in_sizes, int n_in,
                              void* d_out, int out_size, void* d_ws, size_t ws_size,
                              hipStream_t stream)
{
    const float* x       = (const float*)d_in[0];
    const int*   labels  = (const int*)d_in[1];
    const float* centers = (const float*)d_in[2];
    float* out = (float*)d_out;

    const int Bn = in_sizes[1];            // 16384
    const int Dn = in_sizes[0] / Bn;       // 1024

    const int blocks = (Bn + 3) / 4;       // 4096 blocks, 4 samples each
    float* partial = (float*)d_ws;         // Bn * 4 bytes (64 KB) <= ws_size

    prox_partial_kernel<<<blocks, 256, 0, stream>>>(x, labels, centers,
                                                    partial, Bn, Dn);
    prox_final_kernel<<<1, 256, 0, stream>>>(partial, out, Bn,
                                             1.0f / (float)Bn);
}